// Round 1
// baseline (12584.402 us; speedup 1.0000x reference)
//
#include <hip/hip_runtime.h>

// ---------------------------------------------------------------------------
// StackedLstm: 2-layer highway LSTM, B=64, T=512, D=H=1024 (bf16 I/O)
// Recurrence sync: tagged-h dataflow (no grid barriers, no fences).
// h value+step packed in one dword, exchanged via agent-scope atomics (LLC).
// R1: phase-split h loads (all 64 qwords in flight before first tag check,
//     8 serial LLC round trips -> ~1), v_perm unpack, psred double-buffer
//     (drops trailing barrier), publish h before y-store.
// ---------------------------------------------------------------------------

#define DEVINL __device__ __forceinline__

typedef short short8v __attribute__((ext_vector_type(8)));
typedef short short4v __attribute__((ext_vector_type(4)));
typedef float f32x4 __attribute__((ext_vector_type(4)));
typedef unsigned int u32x4 __attribute__((ext_vector_type(4)));

#define Bsz   64
#define Tlen  512
#define Hdim  1024
#define NH5   5120
#define NH6   6144
#define TCH   64          // time-chunk length
#define NCH   8           // chunks per layer
#define XELT  33554432    // B*T*H elements

// d_out element offsets: y1 [B,T,H] | final_h [2,B,H] | final_c [2,B,H]
#define OUT_FH 33554432
#define OUT_FC 33685504

// workspace byte offsets (total ~233.1 MB)
#define WS_XBF    0ULL
#define WS_Y0     67108864ULL
#define WS_WIT0   134217728ULL
#define WS_WIT1   146800640ULL
#define WS_WST0   159383552ULL
#define WS_WST1   169869312ULL
#define WS_PI     180355072ULL
#define WS_HW0    230686720ULL   // 4 slots x 64 x 1024 dwords = 1 MB
#define WS_HW1    231735296ULL   // 1 MB
#define WS_CB     232783872ULL   // 256 KB fp32 c-state
#define WS_DFLAG  233046016ULL

DEVINL short f2bf(float f) {
  unsigned int u = __builtin_bit_cast(unsigned int, f);
  u += 0x7fffu + ((u >> 16) & 1u);          // round-to-nearest-even
  return (short)(u >> 16);
}
DEVINL float bf2f(short s) {
  unsigned int u = ((unsigned int)(unsigned short)s) << 16;
  return __builtin_bit_cast(float, u);
}
DEVINL float fexp2(float x) { return __builtin_amdgcn_exp2f(x); }
DEVINL float frcp(float x)  { return __builtin_amdgcn_rcpf(x); }
DEVINL float sigm(float x)  { return frcp(1.0f + fexp2(-1.44269504f * x)); }
DEVINL float tanh_(float x) { return 1.0f - 2.0f * frcp(1.0f + fexp2(2.88539008f * x)); }

DEVINL void gld_lds16(const short* g, short* lds) {
  __builtin_amdgcn_global_load_lds(
      (const __attribute__((address_space(1))) void*)g,
      (__attribute__((address_space(3))) void*)lds, 16, 0, 0);
}

DEVINL unsigned long long ald64(const unsigned long long* p) {
  return __hip_atomic_load(p, __ATOMIC_RELAXED, __HIP_MEMORY_SCOPE_AGENT);
}
DEVINL unsigned int ald32(const unsigned int* p) {
  return __hip_atomic_load(p, __ATOMIC_RELAXED, __HIP_MEMORY_SCOPE_AGENT);
}
DEVINL void ast32(unsigned int* p, unsigned int v) {
  __hip_atomic_store(p, v, __ATOMIC_RELAXED, __HIP_MEMORY_SCOPE_AGENT);
}

// all 16 tags (8 qwords, 2 dwords each) equal `want` iff AND and OR of the
// tag fields both equal it
DEVINL bool tags_ok(unsigned long long q0, unsigned long long q1,
                    unsigned long long q2, unsigned long long q3,
                    unsigned long long q4, unsigned long long q5,
                    unsigned long long q6, unsigned long long q7,
                    unsigned int want) {
  unsigned long long m = q0 & q1 & q2 & q3 & q4 & q5 & q6 & q7;
  unsigned long long x = q0 | q1 | q2 | q3 | q4 | q5 | q6 | q7;
  return ((unsigned)(m & 0xFFFFu) == want) &
         ((unsigned)((m >> 32) & 0xFFFFu) == want) &
         ((unsigned)(x & 0xFFFFu) == want) &
         ((unsigned)((x >> 32) & 0xFFFFu) == want);
}

// pick hi16 of each dword of q: {lo.hi16, hi.hi16} packed into one dword
DEVINL unsigned int hi16pair(unsigned long long q) {
  return __builtin_amdgcn_perm((unsigned int)(q >> 32), (unsigned int)q,
                               0x07060302u);
}

// ---------------------------------------------------------------------------
// Detect input dtype (bf16 never has exp==0xFF in N(0,1) data) -> dflag.
__global__ void k_detect(const short* __restrict__ x, int* dflag) {
  __shared__ int found;
  if (threadIdx.x == 0) found = 0;
  __syncthreads();
  int hit = 0;
  for (int i = threadIdx.x; i < 16384; i += 256) {
    unsigned int u = (unsigned short)x[i];
    if ((u & 0x7F80u) == 0x7F80u) hit = 1;
  }
  if (hit) atomicOr(&found, 1);
  __syncthreads();
  if (threadIdx.x == 0) *dflag = found;
}

// Zero both tagged-h rings (tags -> 0, h -> +0.0). Agent stores so readers'
// L2-bypassing loads are guaranteed to see them.
__global__ void k_init(unsigned int* hw0, unsigned int* hw1) {
  const int i = (blockIdx.x * 256 + threadIdx.x) * 4;
#pragma unroll
  for (int j = 0; j < 4; ++j) { ast32(hw0 + i + j, 0u); ast32(hw1 + i + j, 0u); }
}

// x -> bf16 copy (converting from fp32 if detected)
__global__ void k_convert(const void* __restrict__ xin, short* __restrict__ xbf,
                          const int* __restrict__ dflag) {
  const int f32 = *dflag;
  const size_t stride = (size_t)gridDim.x * 1024;
  size_t i = ((size_t)blockIdx.x * 256 + threadIdx.x) * 4;
  for (; i < (size_t)XELT; i += stride) {
    short4v v;
    if (f32) {
      const float4 f = *(const float4*)&((const float*)xin)[i];
      v[0] = f2bf(f.x); v[1] = f2bf(f.y); v[2] = f2bf(f.z); v[3] = f2bf(f.w);
    } else {
      v = *(const short4v*)&((const short*)xin)[i];
    }
    *(short4v*)&xbf[i] = v;
  }
}

// (R,C) -> (C,R) bf16 output, dtype-flagged input, 64x64 tiles
__global__ void k_transpose(const void* __restrict__ in, short* __restrict__ out,
                            int R, int C, const int* __restrict__ dflag) {
  __shared__ short tile[64][65];
  const int f32 = *dflag;
  const int r0 = blockIdx.x << 6, c0 = blockIdx.y << 6;
  const int tid = threadIdx.x;
#pragma unroll
  for (int it = 0; it < 8; ++it) {
    int idx = (it << 8) + tid;
    int r = idx >> 5, c2 = (idx & 31) << 1;
    if (f32) {
      const float* inF = (const float*)in;
      tile[r][c2]     = f2bf(inF[(size_t)(r0 + r) * C + c0 + c2]);
      tile[r][c2 + 1] = f2bf(inF[(size_t)(r0 + r) * C + c0 + c2 + 1]);
    } else {
      int v = *(const int*)&((const short*)in)[(size_t)(r0 + r) * C + c0 + c2];
      tile[r][c2]     = (short)(v & 0xffff);
      tile[r][c2 + 1] = (short)(((unsigned)v) >> 16);
    }
  }
  __syncthreads();
#pragma unroll
  for (int it = 0; it < 8; ++it) {
    int idx = (it << 8) + tid;
    int rr = idx >> 5, k2 = (idx & 31) << 1;
    unsigned int lo = (unsigned short)tile[k2][rr];
    unsigned int hi = (unsigned short)tile[k2 + 1][rr];
    *(unsigned int*)&out[(size_t)(c0 + rr) * R + r0 + k2] = lo | (hi << 16);
  }
}

// ---------------------------------------------------------------------------
// pi_chunk[r, 0:6144] = A[row(r), :] @ Bt^T, rows map the chunk's (b, t0+tt).
__launch_bounds__(256)
__global__ void k_gemm(const short* __restrict__ A, const short* __restrict__ Bt,
                       short* __restrict__ Cmat, int t0) {
  __shared__ short ldsA[128 * 64];
  __shared__ short ldsB[128 * 64];
  const int tid = threadIdx.x, lane = tid & 63, wv = tid >> 6;
  const int wm = wv >> 1, wn = wv & 1;
  const int r0 = blockIdx.x * 128;
  const size_t brow0 = (size_t)blockIdx.y * 128;
  f32x4 acc[4][4] = {};

  for (int kk = 0; kk < Hdim; kk += 64) {
#pragma unroll
    for (int p = 0; p < 4; ++p) {
      int slot = ((wv * 4 + p) << 6) + lane;
      int m = slot >> 3, gp = slot & 7;
      int gl = gp ^ (m & 7);
      int r = r0 + m;
      size_t arow = ((size_t)(r >> 6) * Tlen + t0 + (r & 63)) * Hdim;
      gld_lds16(A + arow + kk + (gl << 3), &ldsA[(wv * 4 + p) << 9]);
      gld_lds16(Bt + (brow0 + m) * Hdim + kk + (gl << 3), &ldsB[(wv * 4 + p) << 9]);
    }
    __syncthreads();
#pragma unroll
    for (int kh = 0; kh < 2; ++kh) {
      short8v af[4], bfv[4];
      const int gl = (kh << 2) + (lane >> 4);
#pragma unroll
      for (int mt = 0; mt < 4; ++mt) {
        int m = wm * 64 + mt * 16 + (lane & 15);
        af[mt] = *(const short8v*)&ldsA[m * 64 + ((gl ^ (m & 7)) << 3)];
      }
#pragma unroll
      for (int nt = 0; nt < 4; ++nt) {
        int n = wn * 64 + nt * 16 + (lane & 15);
        bfv[nt] = *(const short8v*)&ldsB[n * 64 + ((gl ^ (n & 7)) << 3)];
      }
#pragma unroll
      for (int mt = 0; mt < 4; ++mt)
#pragma unroll
        for (int nt = 0; nt < 4; ++nt)
          acc[mt][nt] = __builtin_amdgcn_mfma_f32_16x16x32_bf16(af[mt], bfv[nt], acc[mt][nt], 0, 0, 0);
    }
    __syncthreads();
  }
#pragma unroll
  for (int mt = 0; mt < 4; ++mt)
#pragma unroll
    for (int nt = 0; nt < 4; ++nt)
#pragma unroll
      for (int q = 0; q < 4; ++q) {
        size_t row = (size_t)r0 + wm * 64 + mt * 16 + ((lane >> 4) << 2) + q;
        size_t col = brow0 + wn * 64 + nt * 16 + (lane & 15);
        Cmat[row * NH6 + col] = f2bf(acc[mt][nt][q]);
      }
}

// ---------------------------------------------------------------------------
// Persistent recurrent scan, one TCH-step chunk. 256 WGs x 256 threads.
// WG (grp, gbid): batch rows grp*32..+31, hidden units gbid*8..+7.
// h ring: hw[4][64][1024] dwords, dword = (bf16 h << 16) | ((t+1) & 0xFFFF).
__launch_bounds__(256, 1)
__global__ void k_scan(const short* __restrict__ pi, const short* __restrict__ WsT,
                       const void* __restrict__ bs, void* __restrict__ ybase, int yext,
                       void* __restrict__ outb, int fhoff, int fcoff,
                       unsigned int* hw, float* cbuf,
                       int t0, int isfirst,
                       const int* __restrict__ lengths, const int* __restrict__ dflag) {
  extern __shared__ short smem[];
  short* Wt = smem;                                   // 48*1032 shorts
  float* psred = (float*)(smem + 48 * 1032);          // 2 x 24*256 floats

  const int tid  = threadIdx.x, lane = tid & 63, wv = tid >> 6;
  const int bid  = blockIdx.x, grp = bid >> 7, gbid = bid & 127;
  const int rb0  = grp * 32;
  const int u0   = gbid * 8;
  const int f32io = *dflag;
  const int yf32  = yext & f32io;

  // --- one-time: weight slice to LDS (cols packed n = gate*8 + unit)
  for (int n = 0; n < 40; ++n) {
    const short* src = WsT + (size_t)((n >> 3) * Hdim + u0 + (n & 7)) * Hdim;
    *(short4v*)&Wt[n * 1032 + tid * 4] = *(const short4v*)&src[tid * 4];
  }
  short4v zz = {0, 0, 0, 0};
  for (int n = 40; n < 48; ++n) *(short4v*)&Wt[n * 1032 + tid * 4] = zz;

  const int grow = tid >> 3, gunit = tid & 7;
  const int gb = rb0 + grow;
  const int mylen = lengths[gb];
  const unsigned int selfoff = ((unsigned)gb << 10) | (unsigned)(u0 + gunit);

  float bias[5];
  int   psoff[5];
#pragma unroll
  for (int g = 0; g < 5; ++g) {
    bias[g] = f32io ? ((const float*)bs)[g * Hdim + u0 + gunit]
                    : bf2f(((const short*)bs)[g * Hdim + u0 + gunit]);
    int n = g * 8 + gunit, nt = n >> 4, cl = n & 15;
    int mt = grow >> 4, rw = grow & 15;
    int ln = ((rw >> 2) << 4) | cl, reg = rw & 3;
    psoff[g] = ((mt * 3 + nt) << 8) + (ln << 2) + reg;
  }

  // restore own state: h from ring slot (t0-1)&3 (zeros if first), c from cbuf
  float h_state = bf2f((short)(ald32(hw + (((unsigned)(t0 + 3) & 3) << 16) + selfoff) >> 16));
  float c_state = isfirst ? 0.0f : cbuf[(size_t)gb * Hdim + u0 + gunit];

  const int kb = wv << 8;                 // wave's K base (dword index)
  const int klane = (lane >> 4) << 3;

  for (int t = t0; t < t0 + TCH; ++t) {
    const unsigned long long* hs =
        (const unsigned long long*)hw + ((size_t)((t + 3) & 3) << 15);
    const unsigned int want = (unsigned)(t & 0xFFFF);
    // per-lane qword base: row (rb0 + lane&15), k = kb + klane
    const unsigned long long* pb =
        hs + (((size_t)(rb0 + (lane & 15))) << 9) + ((kb + klane) >> 1);

    // --- phase 1: issue ALL h loads (64 qwords/lane) before any tag check.
    // Converts 8 serial LLC round trips into ~1. 128 VGPRs is free at
    // 1 WG/CU (LDS-capped), 1 wave/SIMD.
    unsigned long long q[8][8];
#pragma unroll
    for (int ks = 0; ks < 8; ++ks) {
      const unsigned long long* p0 = pb + ks * 16;
#pragma unroll
      for (int j = 0; j < 4; ++j) {
        q[ks][j]     = ald64(p0 + j);
        q[ks][4 + j] = ald64(p0 + (16 << 9) + j);
      }
    }

    // pi loads (independent of h; issue behind the h loads)
    const short* pib = pi + (size_t)(gb * TCH + (t - t0)) * NH6 + u0 + gunit;
    float piv[6];
#pragma unroll
    for (int g = 0; g < 6; ++g) piv[g] = bf2f(pib[g << 10]);

    // --- phase 2: validate chunks in completion order (retry = cold path),
    // then MFMA.
    f32x4 acc[2][3] = {};
#pragma unroll
    for (int ks = 0; ks < 8; ++ks) {
      bool ok = tags_ok(q[ks][0], q[ks][1], q[ks][2], q[ks][3],
                        q[ks][4], q[ks][5], q[ks][6], q[ks][7], want);
      while (!ok) {
        const unsigned long long* p0 = pb + ks * 16;
#pragma unroll
        for (int j = 0; j < 4; ++j) {
          q[ks][j]     = ald64(p0 + j);
          q[ks][4 + j] = ald64(p0 + (16 << 9) + j);
        }
        ok = tags_ok(q[ks][0], q[ks][1], q[ks][2], q[ks][3],
                     q[ks][4], q[ks][5], q[ks][6], q[ks][7], want);
      }
      u32x4 ua, ub;
#pragma unroll
      for (int j = 0; j < 4; ++j) {
        ua[j] = hi16pair(q[ks][j]);
        ub[j] = hi16pair(q[ks][4 + j]);
      }
      short8v a0 = __builtin_bit_cast(short8v, ua);
      short8v a1 = __builtin_bit_cast(short8v, ub);
      const int k = kb + (ks << 5) + klane;
#pragma unroll
      for (int nt = 0; nt < 3; ++nt) {
        short8v bfv = *(const short8v*)&Wt[(nt * 16 + (lane & 15)) * 1032 + k];
        acc[0][nt] = __builtin_amdgcn_mfma_f32_16x16x32_bf16(a0, bfv, acc[0][nt], 0, 0, 0);
        acc[1][nt] = __builtin_amdgcn_mfma_f32_16x16x32_bf16(a1, bfv, acc[1][nt], 0, 0, 0);
      }
    }

    // psred double-buffered by (t&1): no trailing barrier needed.
    float* ps_w = psred + ((t & 1) * 6144);
#pragma unroll
    for (int mt = 0; mt < 2; ++mt)
#pragma unroll
      for (int nt = 0; nt < 3; ++nt)
        *(f32x4*)&ps_w[((wv * 6 + mt * 3 + nt) << 8) + (lane << 2)] = acc[mt][nt];
    __syncthreads();

    float ps[5];
#pragma unroll
    for (int g = 0; g < 5; ++g) {
      int o = psoff[g];
      ps[g] = bias[g] + ps_w[o] + ps_w[1536 + o] + ps_w[3072 + o] + ps_w[4608 + o];
    }
    float ig = sigm(piv[0] + ps[0]);
    float fg = sigm(piv[1] + ps[1]);
    float mg = tanh_(piv[2] + ps[2]);
    float og = sigm(piv[3] + ps[3]);
    float hw_g = sigm(piv[4] + ps[4]);
    float cn  = ig * mg + fg * c_state;
    float outv = og * tanh_(cn);
    outv = hw_g * outv + (1.0f - hw_g) * piv[5];
    const bool valid = (t < mylen);
    if (valid) { c_state = cn; h_state = outv; }

    // publish h(t) tagged t+1 into ring slot t&3 FIRST (atomic dword:
    // tag+data together) -- readers see it ~100ns earlier than post-y-store
    unsigned int pk = (((unsigned)(unsigned short)f2bf(h_state)) << 16) |
                      ((unsigned)((t + 1) & 0xFFFF));
    ast32(hw + (((unsigned)t & 3) << 16) + selfoff, pk);

    size_t yi = ((size_t)gb * Tlen + t) * Hdim + u0 + gunit;
    if (yf32) ((float*)ybase)[yi] = valid ? outv : 0.0f;
    else      ((short*)ybase)[yi] = valid ? f2bf(outv) : (short)0;
  }

  cbuf[(size_t)gb * Hdim + u0 + gunit] = c_state;
  const size_t sidx = (size_t)gb * Hdim + u0 + gunit;
  if (f32io) {
    ((float*)outb)[fhoff + sidx] = h_state;
    ((float*)outb)[fcoff + sidx] = c_state;
  } else {
    ((short*)outb)[fhoff + sidx] = f2bf(h_state);
    ((short*)outb)[fcoff + sidx] = f2bf(c_state);
  }
}

// ---------------------------------------------------------------------------
extern "C" void kernel_launch(void* const* d_in, const int* in_sizes, int n_in,
                              void* d_out, int out_size, void* d_ws, size_t ws_size,
                              hipStream_t stream) {
  const void* x       = d_in[0];
  const int*  lengths = (const int*)d_in[1];
  const void* Wi0     = d_in[2];
  const void* Ws0     = d_in[3];
  const void* bs0     = d_in[4];
  const void* Wi1     = d_in[5];
  const void* Ws1     = d_in[6];
  const void* bs1     = d_in[7];
  char* ws = (char*)d_ws;

  short* xbf   = (short*)(ws + WS_XBF);
  short* y0    = (short*)(ws + WS_Y0);
  short* WiT0  = (short*)(ws + WS_WIT0);
  short* WiT1  = (short*)(ws + WS_WIT1);
  short* WsT0  = (short*)(ws + WS_WST0);
  short* WsT1  = (short*)(ws + WS_WST1);
  short* pibuf = (short*)(ws + WS_PI);
  unsigned int* hw0 = (unsigned int*)(ws + WS_HW0);
  unsigned int* hw1 = (unsigned int*)(ws + WS_HW1);
  float* cbuf  = (float*)(ws + WS_CB);
  int*   dflag = (int*)(ws + WS_DFLAG);

  k_detect<<<1, 256, 0, stream>>>((const short*)x, dflag);
  k_init<<<256, 256, 0, stream>>>(hw0, hw1);
  k_convert<<<2048, 256, 0, stream>>>(x, xbf, dflag);
  k_transpose<<<dim3(16, 96), 256, 0, stream>>>(Wi0, WiT0, 1024, NH6, dflag);
  k_transpose<<<dim3(16, 80), 256, 0, stream>>>(Ws0, WsT0, 1024, NH5, dflag);
  k_transpose<<<dim3(16, 96), 256, 0, stream>>>(Wi1, WiT1, 1024, NH6, dflag);
  k_transpose<<<dim3(16, 80), 256, 0, stream>>>(Ws1, WsT1, 1024, NH5, dflag);

  const unsigned int scan_lds = 48 * 1032 * 2 + 2 * 24 * 256 * 4;  // 148,224 B
  hipFuncSetAttribute((const void*)k_scan, hipFuncAttributeMaxDynamicSharedMemorySize,
                      (int)scan_lds);

  for (int layer = 0; layer < 2; ++layer) {
    const short* Asrc = (layer == 0) ? xbf : y0;
    const short* WiT  = (layer == 0) ? WiT0 : WiT1;
    const short* WsT  = (layer == 0) ? WsT0 : WsT1;
    const void*  bsp  = (layer == 0) ? bs0 : bs1;
    unsigned int* hwp = (layer == 0) ? hw0 : hw1;
    for (int c = 0; c < NCH; ++c) {
      k_gemm<<<dim3(32, 48), 256, 0, stream>>>(Asrc, WiT, pibuf, c * TCH);

      const short* pi_p = pibuf; const short* ws_p = WsT; const void* bs_p = bsp;
      void* y_p  = (layer == 0) ? (void*)y0 : d_out;
      int yext   = (layer == 0) ? 0 : 1;
      void* outp = d_out;
      int fh = OUT_FH + layer * 65536, fcv = OUT_FC + layer * 65536;
      unsigned int* hwq = hwp; float* cb = cbuf;
      int tt0 = c * TCH;
      int isf = (c == 0) ? 1 : 0;
      const int* len = lengths; const int* df = dflag;
      void* args[14] = {&pi_p, &ws_p, &bs_p, &y_p, &yext, &outp, &fh, &fcv,
                        &hwq, &cb, &tt0, &isf, &len, &df};
      hipLaunchCooperativeKernel((void*)k_scan, dim3(256), dim3(256), args,
                                 scan_lds, stream);
    }
  }
}